// Round 1
// baseline (1226.151 us; speedup 1.0000x reference)
//
#include <hip/hip_runtime.h>

// ---------------------------------------------------------------------------
// Fused actor-critic forward on MI355X (gfx950), all fp32 (no fp32 MFMA on
// CDNA4 -> VALU). One kernel, 64 batch rows per 256-thread workgroup.
//
// Phases (all intermediates stay in LDS):
//  P1  trunk GEMM  Y[64][192] = X[64][376] @ [cW1;aW1;nW1]^T   (K-chunked, 8x47)
//  E1  silu (+rmsnorm for critic/noise trunks), in-place, transposed tiles
//  P2  3x  [64,64]@[64,64] GEMMs (cW2,aW2,nW2), staged+swizzled weights
//  E2  silu (+rms noise) ; critic value = reduce(h2*cW3)+cb3 -> out
//  P3  nfW GEMM -> sigma^2 tile ; amW head GEMM -> diff = action-mean ; action copy
//  P4  gram GEMM  G[64][153] = S2[64][64] @ P[64][153]  (P = wdir pair products)
//  P5  17x17 Cholesky + forward solve, 17-lane groups (3 rows/wave), unrolled
// ---------------------------------------------------------------------------

#define BB   131072
#define OBSD 376

static constexpr float EPS_RMS  = 1.19209290e-07f;
static constexpr float LOG2PI_F = 1.8378770664093453f;

// ---- LDS layout (float offsets), regions are unioned across phases ----
static constexpr int ATT  = 0;      // [3][64][68] trunk act tiles (stride 68)   = 13056
static constexpr int XS   = 0;      // P1: x chunk [47][68]                       = 3196
static constexpr int WS3  = 3196;   // P1: W chunk [47][196]                      = 9212
static constexpr int PTB  = 0;      // P4: pair products [64][192]                = 12288
static constexpr int GBB  = 0;      // P5: gram [64][154]                         = 9856
static constexpr int WSTO = 13056;  // [64][68]: W2 staging (swz) / sigma^2 tile  = 4352
static constexpr int WHDO = 17408;  // [64][20]: amW^T staging / DIFF buffer      = 1280
static constexpr int SBX  = 18688;  // 10 x 64 biases/gains
static constexpr int SAMB = 19328;  // amb[17]
static constexpr int SCB3 = 19345;  // cb3
static constexpr int SCW3 = 19346;  // cW3[64]
static constexpr int SRN  = 19410;  // 1/(||amW_a||+1e-8) [17]
static constexpr int SMEMF = 19432; // total floats -> 77728 bytes (2 WG/CU)

union F4 { float4 v; float a[4]; };

__device__ __forceinline__ float silu_f(float z) {
  return z / (1.0f + expf(-z));
}

__global__ __launch_bounds__(256, 2) void fused_ac(
    const float* __restrict__ x,   const float* __restrict__ actv,
    const float* __restrict__ cW1, const float* __restrict__ cb1, const float* __restrict__ cg1,
    const float* __restrict__ cW2, const float* __restrict__ cb2,
    const float* __restrict__ cW3, const float* __restrict__ cb3,
    const float* __restrict__ aW1, const float* __restrict__ ab1,
    const float* __restrict__ aW2, const float* __restrict__ ab2,
    const float* __restrict__ amW, const float* __restrict__ amb,
    const float* __restrict__ nW1, const float* __restrict__ nb1, const float* __restrict__ ng1,
    const float* __restrict__ nW2, const float* __restrict__ nb2, const float* __restrict__ ng2,
    const float* __restrict__ nfW, const float* __restrict__ nfb,
    float* __restrict__ out)
{
  extern __shared__ float sm[];
  const int tid  = (int)threadIdx.x;
  const int tc   = tid & 15;     // col group (16)
  const int tr   = tid >> 4;     // row group (16): rows 4*tr..4*tr+3
  const int lane = tid & 63;
  const int wv   = tid >> 6;
  const long rowbase = (long)blockIdx.x << 6;

  // ---- stage small params / compute amW row norms ----
  if (tid < 64) {
    sm[SBX + 0*64 + tid] = cb1[tid];
    sm[SBX + 1*64 + tid] = cg1[tid];
    sm[SBX + 2*64 + tid] = ab1[tid];
    sm[SBX + 3*64 + tid] = nb1[tid];
    sm[SBX + 4*64 + tid] = ng1[tid];
    sm[SBX + 5*64 + tid] = cb2[tid];
    sm[SBX + 6*64 + tid] = ab2[tid];
    sm[SBX + 7*64 + tid] = nb2[tid];
    sm[SBX + 8*64 + tid] = ng2[tid];
    sm[SBX + 9*64 + tid] = nfb[tid];
    sm[SCW3 + tid] = cW3[tid];
  } else if (tid < 81) {
    sm[SAMB + (tid - 64)] = amb[tid - 64];
  } else if (tid == 81) {
    sm[SCB3] = cb3[0];
  } else if (tid >= 128 && tid < 145) {
    const int a = tid - 128;
    float s = 0.0f;
    for (int h = 0; h < 64; ++h) { const float w = amW[a*64 + h]; s = fmaf(w, w, s); }
    sm[SRN + a] = 1.0f / (sqrtf(s) + 1e-8f);
  }

  // =================== P1: trunk GEMM [64x376] @ [376x192] ===================
  float acc1[12][4];
  #pragma unroll
  for (int cc = 0; cc < 12; ++cc)
    #pragma unroll
    for (int rr = 0; rr < 4; ++rr) acc1[cc][rr] = 0.0f;

  for (int ch = 0; ch < 8; ++ch) {
    const int kc = ch * 47;
    __syncthreads();
    for (int i = tid; i < 64*47; i += 256) {
      const int row = i / 47;
      const int k   = i - row*47;
      sm[XS + k*68 + row] = x[(rowbase + row)*OBSD + kc + k];
    }
    for (int i = tid; i < 192*47; i += 256) {
      const int cix = i / 47;
      const int k   = i - cix*47;
      const int t   = cix >> 6;
      const float* w = (t == 0) ? cW1 : ((t == 1) ? aW1 : nW1);
      sm[WS3 + k*196 + cix] = w[(cix & 63)*OBSD + kc + k];
    }
    __syncthreads();
    for (int k = 0; k < 47; ++k) {
      F4 xv; xv.v = *(const float4*)&sm[XS + k*68 + 4*tr];
      const float* wp = &sm[WS3 + k*196 + 12*tc];
      F4 w0, w1, w2;
      w0.v = *(const float4*)(wp + 0);
      w1.v = *(const float4*)(wp + 4);
      w2.v = *(const float4*)(wp + 8);
      #pragma unroll
      for (int cc = 0; cc < 4; ++cc)
        #pragma unroll
        for (int rr = 0; rr < 4; ++rr) {
          acc1[cc + 0][rr] = fmaf(w0.a[cc], xv.a[rr], acc1[cc + 0][rr]);
          acc1[cc + 4][rr] = fmaf(w1.a[cc], xv.a[rr], acc1[cc + 4][rr]);
          acc1[cc + 8][rr] = fmaf(w2.a[cc], xv.a[rr], acc1[cc + 8][rr]);
        }
    }
  }
  __syncthreads();
  // write pre-activations transposed: ATT[t][h][row]
  #pragma unroll
  for (int cc = 0; cc < 12; ++cc) {
    const int c = 12*tc + cc;
    const int t = c >> 6, h = c & 63;
    F4 v;
    #pragma unroll
    for (int rr = 0; rr < 4; ++rr) v.a[rr] = acc1[cc][rr];
    *(float4*)&sm[ATT + t*4352 + h*68 + 4*tr] = v.v;
  }
  __syncthreads();

  // =================== E1: silu (+rms) in place ===================
  #pragma unroll 1
  for (int rb = 0; rb < 4; ++rb) {
    const int r0 = wv*16 + rb*4;
    { // critic: rmsnorm(silu(.+cb1), cg1)
      F4 y; y.v = *(const float4*)&sm[ATT + 0*4352 + lane*68 + r0];
      const float b = sm[SBX + 0*64 + lane], g = sm[SBX + 1*64 + lane];
      float vv[4], ss[4];
      #pragma unroll
      for (int rr = 0; rr < 4; ++rr) { const float s = silu_f(y.a[rr] + b); vv[rr] = s; ss[rr] = s*s; }
      #pragma unroll
      for (int m = 1; m < 64; m <<= 1)
        #pragma unroll
        for (int rr = 0; rr < 4; ++rr) ss[rr] += __shfl_xor(ss[rr], m, 64);
      F4 o;
      #pragma unroll
      for (int rr = 0; rr < 4; ++rr) o.a[rr] = vv[rr] * rsqrtf(ss[rr]*(1.0f/64.0f) + EPS_RMS) * g;
      *(float4*)&sm[ATT + 0*4352 + lane*68 + r0] = o.v;
    }
    { // actor: silu only
      F4 y; y.v = *(const float4*)&sm[ATT + 1*4352 + lane*68 + r0];
      const float b = sm[SBX + 2*64 + lane];
      F4 o;
      #pragma unroll
      for (int rr = 0; rr < 4; ++rr) o.a[rr] = silu_f(y.a[rr] + b);
      *(float4*)&sm[ATT + 1*4352 + lane*68 + r0] = o.v;
    }
    { // noise: rmsnorm(silu(.+nb1), ng1)
      F4 y; y.v = *(const float4*)&sm[ATT + 2*4352 + lane*68 + r0];
      const float b = sm[SBX + 3*64 + lane], g = sm[SBX + 4*64 + lane];
      float vv[4], ss[4];
      #pragma unroll
      for (int rr = 0; rr < 4; ++rr) { const float s = silu_f(y.a[rr] + b); vv[rr] = s; ss[rr] = s*s; }
      #pragma unroll
      for (int m = 1; m < 64; m <<= 1)
        #pragma unroll
        for (int rr = 0; rr < 4; ++rr) ss[rr] += __shfl_xor(ss[rr], m, 64);
      F4 o;
      #pragma unroll
      for (int rr = 0; rr < 4; ++rr) o.a[rr] = vv[rr] * rsqrtf(ss[rr]*(1.0f/64.0f) + EPS_RMS) * g;
      *(float4*)&sm[ATT + 2*4352 + lane*68 + r0] = o.v;
    }
  }
  __syncthreads();

  // =================== P2: three 64x64 GEMMs ===================
  float acc2_0[4][4], acc2_1[4][4], acc2_2[4][4];
  #pragma unroll
  for (int cc = 0; cc < 4; ++cc)
    #pragma unroll
    for (int rr = 0; rr < 4; ++rr) { acc2_0[cc][rr] = 0.f; acc2_1[cc][rr] = 0.f; acc2_2[cc][rr] = 0.f; }

#define GEMM2_STEP(T, WP, ACC) do {                                              \
    for (int i = tid; i < 4096; i += 256) {                                      \
      const int j = i >> 6, h = i & 63;                                          \
      sm[WSTO + h*68 + (j ^ ((h & 7) << 2))] = (WP)[i];                          \
    }                                                                            \
    __syncthreads();                                                             \
    for (int h = 0; h < 64; ++h) {                                               \
      F4 a4; a4.v = *(const float4*)&sm[ATT + (T)*4352 + h*68 + 4*tr];           \
      F4 w4; w4.v = *(const float4*)&sm[WSTO + h*68 + ((4*tc) ^ ((h & 7) << 2))];\
      _Pragma("unroll")                                                          \
      for (int cc = 0; cc < 4; ++cc)                                             \
        _Pragma("unroll")                                                        \
        for (int rr = 0; rr < 4; ++rr)                                           \
          ACC[cc][rr] = fmaf(w4.a[cc], a4.a[rr], ACC[cc][rr]);                   \
    }                                                                            \
    __syncthreads();                                                             \
  } while (0)

  GEMM2_STEP(0, cW2, acc2_0);
  GEMM2_STEP(1, aW2, acc2_1);
  GEMM2_STEP(2, nW2, acc2_2);

  // write layer-2 pre-activations transposed: ATT[t][j][row]  (aliases A1T, now dead)
#define ST_A2T(T, ACC) do {                                                      \
    _Pragma("unroll")                                                            \
    for (int cc = 0; cc < 4; ++cc) {                                             \
      const int j = 4*tc + cc;                                                   \
      F4 v;                                                                      \
      _Pragma("unroll")                                                          \
      for (int rr = 0; rr < 4; ++rr) v.a[rr] = ACC[cc][rr];                      \
      *(float4*)&sm[ATT + (T)*4352 + j*68 + 4*tr] = v.v;                         \
    }                                                                            \
  } while (0)
  ST_A2T(0, acc2_0);
  ST_A2T(1, acc2_1);
  ST_A2T(2, acc2_2);
  __syncthreads();

  // =================== E2: activations + value output ===================
  #pragma unroll 1
  for (int rb = 0; rb < 4; ++rb) {
    const int r0 = wv*16 + rb*4;
    { // critic: value = sum(silu(.+cb2) * cW3) + cb3
      F4 y; y.v = *(const float4*)&sm[ATT + 0*4352 + lane*68 + r0];
      const float b = sm[SBX + 5*64 + lane], w3 = sm[SCW3 + lane];
      float pv[4];
      #pragma unroll
      for (int rr = 0; rr < 4; ++rr) pv[rr] = silu_f(y.a[rr] + b) * w3;
      #pragma unroll
      for (int m = 1; m < 64; m <<= 1)
        #pragma unroll
        for (int rr = 0; rr < 4; ++rr) pv[rr] += __shfl_xor(pv[rr], m, 64);
      if (lane == 0) {
        const float c3 = sm[SCB3];
        #pragma unroll
        for (int rr = 0; rr < 4; ++rr)
          out[(size_t)BB*19 + (size_t)(rowbase + r0 + rr)] = pv[rr] + c3;
      }
    }
    { // actor: l2 = silu(.+ab2)
      F4 y; y.v = *(const float4*)&sm[ATT + 1*4352 + lane*68 + r0];
      const float b = sm[SBX + 6*64 + lane];
      F4 o;
      #pragma unroll
      for (int rr = 0; rr < 4; ++rr) o.a[rr] = silu_f(y.a[rr] + b);
      *(float4*)&sm[ATT + 1*4352 + lane*68 + r0] = o.v;
    }
    { // noise: n2 = rmsnorm(silu(.+nb2), ng2)
      F4 y; y.v = *(const float4*)&sm[ATT + 2*4352 + lane*68 + r0];
      const float b = sm[SBX + 7*64 + lane], g = sm[SBX + 8*64 + lane];
      float vv[4], ss[4];
      #pragma unroll
      for (int rr = 0; rr < 4; ++rr) { const float s = silu_f(y.a[rr] + b); vv[rr] = s; ss[rr] = s*s; }
      #pragma unroll
      for (int m = 1; m < 64; m <<= 1)
        #pragma unroll
        for (int rr = 0; rr < 4; ++rr) ss[rr] += __shfl_xor(ss[rr], m, 64);
      F4 o;
      #pragma unroll
      for (int rr = 0; rr < 4; ++rr) o.a[rr] = vv[rr] * rsqrtf(ss[rr]*(1.0f/64.0f) + EPS_RMS) * g;
      *(float4*)&sm[ATT + 2*4352 + lane*68 + r0] = o.v;
    }
  }
  __syncthreads();

  // =================== P3: nfW GEMM + heads ===================
  for (int i = tid; i < 4096; i += 256) {
    const int j = i >> 6, h = i & 63;
    sm[WSTO + h*68 + (j ^ ((h & 7) << 2))] = nfW[i];
  }
  for (int i = tid; i < 1088; i += 256) {
    const int a = i >> 6, h = i & 63;
    sm[WHDO + h*20 + a] = amW[i];
  }
  __syncthreads();

  float acc3n[4][4];
  #pragma unroll
  for (int cc = 0; cc < 4; ++cc)
    #pragma unroll
    for (int rr = 0; rr < 4; ++rr) acc3n[cc][rr] = 0.f;
  for (int h = 0; h < 64; ++h) {
    F4 a4; a4.v = *(const float4*)&sm[ATT + 2*4352 + h*68 + 4*tr];
    F4 w4; w4.v = *(const float4*)&sm[WSTO + h*68 + ((4*tc) ^ ((h & 7) << 2))];
    #pragma unroll
    for (int cc = 0; cc < 4; ++cc)
      #pragma unroll
      for (int rr = 0; rr < 4; ++rr) acc3n[cc][rr] = fmaf(w4.a[cc], a4.a[rr], acc3n[cc][rr]);
  }
  float acc3h[4][4];
  #pragma unroll
  for (int cc = 0; cc < 4; ++cc)
    #pragma unroll
    for (int rr = 0; rr < 4; ++rr) acc3h[cc][rr] = 0.f;
  if (tc < 5) {
    for (int h = 0; h < 64; ++h) {
      F4 a4; a4.v = *(const float4*)&sm[ATT + 1*4352 + h*68 + 4*tr];
      F4 w4; w4.v = *(const float4*)&sm[WHDO + h*20 + 4*tc];
      #pragma unroll
      for (int cc = 0; cc < 4; ++cc)
        #pragma unroll
        for (int rr = 0; rr < 4; ++rr) acc3h[cc][rr] = fmaf(w4.a[cc], a4.a[rr], acc3h[cc][rr]);
    }
  }
  __syncthreads();

  // sigma^2 tile into WSTO (nfW staging dead)
  #pragma unroll
  for (int cc = 0; cc < 4; ++cc) {
    const int j = 4*tc + cc;
    const float nb = sm[SBX + 9*64 + j];
    F4 v;
    #pragma unroll
    for (int rr = 0; rr < 4; ++rr)
      v.a[rr] = expf(2.0f * fminf(acc3n[cc][rr] + nb, 5.0f));
    *(float4*)&sm[WSTO + j*68 + 4*tr] = v.v;
  }
  // heads epilogue: action copy + diff into WHDO (amW^T staging dead)
  if (tc < 5) {
    #pragma unroll
    for (int cc = 0; cc < 4; ++cc) {
      const int c = 4*tc + cc;
      if (c < 17) {
        const float mb = sm[SAMB + c];
        #pragma unroll
        for (int rr = 0; rr < 4; ++rr) {
          const int lr = 4*tr + rr;
          const size_t grow = (size_t)(rowbase + lr);
          const float mean = acc3h[cc][rr] + mb;
          const float av = actv[grow*17 + c];
          out[grow*17 + c] = av;
          sm[WHDO + lr*20 + c] = av - mean;
        }
      }
    }
  }
  // pair-product table PT[h][p] into ATT region (A2T dead)
  for (int i = tid; i < 9792; i += 256) {
    const int h = i / 153;
    const int p = i - h*153;
    int a = (int)((sqrtf(8.0f*(float)p + 1.0f) - 1.0f) * 0.5f);
    if ((a + 1)*(a + 2)/2 <= p) ++a;
    if (a*(a + 1)/2 > p) --a;
    const int c = p - a*(a + 1)/2;
    sm[PTB + h*192 + p] = amW[a*64 + h] * amW[c*64 + h] * sm[SRN + a] * sm[SRN + c];
  }
  __syncthreads();

  // =================== P4: gram GEMM [64,64]@[64,153] ===================
  float acc4[12][4];
  #pragma unroll
  for (int cc = 0; cc < 12; ++cc)
    #pragma unroll
    for (int rr = 0; rr < 4; ++rr) acc4[cc][rr] = 0.f;
  for (int h = 0; h < 64; ++h) {
    F4 s4; s4.v = *(const float4*)&sm[WSTO + h*68 + 4*tr];
    const float* pp = &sm[PTB + h*192 + 12*tc];
    F4 p0, p1, p2;
    p0.v = *(const float4*)(pp + 0);
    p1.v = *(const float4*)(pp + 4);
    p2.v = *(const float4*)(pp + 8);
    #pragma unroll
    for (int cc = 0; cc < 4; ++cc)
      #pragma unroll
      for (int rr = 0; rr < 4; ++rr) {
        acc4[cc + 0][rr] = fmaf(p0.a[cc], s4.a[rr], acc4[cc + 0][rr]);
        acc4[cc + 4][rr] = fmaf(p1.a[cc], s4.a[rr], acc4[cc + 4][rr]);
        acc4[cc + 8][rr] = fmaf(p2.a[cc], s4.a[rr], acc4[cc + 8][rr]);
      }
  }
  __syncthreads();
  #pragma unroll
  for (int cc = 0; cc < 12; ++cc) {
    const int p = 12*tc + cc;
    if (p < 153) {
      #pragma unroll
      for (int rr = 0; rr < 4; ++rr)
        sm[GBB + (4*tr + rr)*154 + p] = acc4[cc][rr];
    }
  }
  __syncthreads();

  // =================== P5: Cholesky + solve, 17-lane groups ===================
  {
    const int g  = lane / 17;        // 0..3 (g==3 idle)
    const int j  = lane - g*17;      // 0..16
    const int gb = g*17;
    const int jb = j*(j + 1)/2;
    #pragma unroll 1
    for (int t6 = 0; t6 < 6; ++t6) {
      const int rl = 3*t6 + g;
      const bool valid = (g < 3) && (rl < 16);
      const int rloc = wv*16 + (valid ? rl : 0);
      float L[17];
      #pragma unroll
      for (int i = 0; i <= 16; ++i) {
        const float vv = (j >= i) ? sm[GBB + rloc*154 + jb + i] : 0.0f;
        L[i] = vv + ((i == j) ? 1e-4f : 0.0f);
      }
      float d = sm[WHDO + rloc*20 + j];
      float mylog = 0.0f, myinv = 0.0f, yown = 0.0f;
      #pragma unroll
      for (int k = 0; k <= 16; ++k) {
        const float akk = __shfl(L[k], gb + k, 64);
        const float rsq = rsqrtf(akk);
        if (j == k) { L[k] = akk * rsq; mylog = 0.5f * logf(akk); myinv = rsq; }
        if (j > k)  { L[k] *= rsq; }
        #pragma unroll
        for (int i = k + 1; i <= 16; ++i) {
          const float lik = __shfl(L[k], gb + i, 64);
          if (j >= i) L[i] = fmaf(-L[k], lik, L[i]);
        }
      }
      #pragma unroll
      for (int i = 0; i <= 16; ++i) {
        const float yi = __shfl(d * myinv, gb + i, 64);
        if (j == i) yown = yi;
        if (j > i)  d = fmaf(-L[i], yi, d);
      }
      const float y2 = yown * yown;
      float ms = 0.0f, ls = 0.0f;
      #pragma unroll
      for (int jj = 0; jj <= 16; ++jj) {
        ms += __shfl(y2,    gb + jj, 64);
        ls += __shfl(mylog, gb + jj, 64);
      }
      if (valid && j == 0) {
        const size_t grow = (size_t)(rowbase + rloc);
        out[(size_t)BB*17 + grow] = -0.5f * (17.0f*LOG2PI_F + 2.0f*ls + ms);
        out[(size_t)BB*18 + grow] =  0.5f * (17.0f*(1.0f + LOG2PI_F) + 2.0f*ls);
      }
    }
  }
}

extern "C" void kernel_launch(void* const* d_in, const int* in_sizes, int n_in,
                              void* d_out, int out_size, void* d_ws, size_t ws_size,
                              hipStream_t stream) {
  (void)in_sizes; (void)n_in; (void)d_ws; (void)ws_size; (void)out_size;
  const float* x   = (const float*)d_in[0];
  const float* acv = (const float*)d_in[1];
  const float* cW1 = (const float*)d_in[2];
  const float* cb1 = (const float*)d_in[3];
  const float* cg1 = (const float*)d_in[4];
  const float* cW2 = (const float*)d_in[5];
  const float* cb2 = (const float*)d_in[6];
  const float* cW3 = (const float*)d_in[7];
  const float* cb3 = (const float*)d_in[8];
  const float* aW1 = (const float*)d_in[9];
  const float* ab1 = (const float*)d_in[10];
  const float* aW2 = (const float*)d_in[11];
  const float* ab2 = (const float*)d_in[12];
  const float* amW = (const float*)d_in[13];
  const float* amb = (const float*)d_in[14];
  const float* nW1 = (const float*)d_in[15];
  const float* nb1 = (const float*)d_in[16];
  const float* ng1 = (const float*)d_in[17];
  const float* nW2 = (const float*)d_in[18];
  const float* nb2 = (const float*)d_in[19];
  const float* ng2 = (const float*)d_in[20];
  const float* nfW = (const float*)d_in[21];
  const float* nfb = (const float*)d_in[22];
  float* out = (float*)d_out;

  const int smem_bytes = SMEMF * 4;
  hipFuncSetAttribute((const void*)fused_ac,
                      hipFuncAttributeMaxDynamicSharedMemorySize, smem_bytes);
  fused_ac<<<dim3(BB/64), dim3(256), smem_bytes, stream>>>(
      x, acv, cW1, cb1, cg1, cW2, cb2, cW3, cb3,
      aW1, ab1, aW2, ab2, amW, amb,
      nW1, nb1, ng1, nW2, nb2, ng2, nfW, nfb, out);
}

// Round 3
// 891.465 us; speedup vs baseline: 1.3754x; 1.3754x over previous
//
#include <hip/hip_runtime.h>

// ---------------------------------------------------------------------------
// Fused actor-critic forward on MI355X (gfx950).
// Trunk GEMM (70% of FLOPs) runs on MFMA via split-bf16 (hi/lo) for fp32-grade
// accuracy; the rest stays fp32 VALU. amdgpu_waves_per_eu(2,2) pins the
// register allocator to the LDS-limited occupancy (2 blocks/CU) so the
// accumulators stay in VGPRs (round-1 pathology: VGPR_Count=60 -> AGPR shuffle,
// 3x VALU inflation).
// ---------------------------------------------------------------------------

#define BB   131072
#define OBSD 376

typedef short bf16x8 __attribute__((ext_vector_type(8)));
typedef float f32x4  __attribute__((ext_vector_type(4)));

static constexpr float EPS_RMS  = 1.19209290e-07f;
static constexpr float LOG2PI_F = 1.8378770664093453f;

// ---- LDS layout (float offsets), regions unioned across phases ----
static constexpr int SBX  = 0;      // 10 x 64 biases/gains
static constexpr int SAMB = 640;    // amb[17]
static constexpr int SCB3 = 657;    // cb3
static constexpr int SCW3 = 658;    // cW3[64]
static constexpr int SRN  = 722;    // 1/(||amW_a||+1e-8) [17] -> ends 739
// persistent ends < 768
static constexpr int XH   = 768;          // x hi bf16 frags, 2048 f (8KB)
static constexpr int XL   = 768 + 2048;   // x lo
static constexpr int WHS  = 768 + 4096;   // W hi, 6144 f (24KB)
static constexpr int WLS  = 768 + 10240;  // W lo   -> staging ends 17152
static constexpr int ATT  = 768;    // [3][64][68] act tiles = 13056 -> ends 13824
static constexpr int PTB  = 768;    // P4 pair products [64][192] = 12288
static constexpr int GBB  = 768;    // P5 gram [64][154] = 9856
static constexpr int WSTO = 13824;  // [64][68] W2 staging(swz) / sigma^2 tile
static constexpr int WHDO = 18176;  // [64][20] amW^T staging / DIFF buffer
static constexpr int SMEMF = 19456; // 77824 bytes -> 2 WG/CU

union F4 { float4 v; float a[4]; };

__device__ __forceinline__ float silu_f(float z) {
  return z / (1.0f + expf(-z));
}

__device__ __forceinline__ unsigned bfround(float f) {
  const unsigned u = __float_as_uint(f);
  return (u + 0x7fffu + ((u >> 16) & 1u)) >> 16;
}

// split 8 fp32 -> 8 bf16 hi + 8 bf16 lo (packed 16B each)
__device__ __forceinline__ void split8(const float* v, uint4& ph, uint4& pl) {
  unsigned h[8], l[8];
  #pragma unroll
  for (int j = 0; j < 8; ++j) {
    h[j] = bfround(v[j]);
    const float fh = __uint_as_float(h[j] << 16);
    l[j] = bfround(v[j] - fh);
  }
  ph = make_uint4(h[0] | (h[1] << 16), h[2] | (h[3] << 16),
                  h[4] | (h[5] << 16), h[6] | (h[7] << 16));
  pl = make_uint4(l[0] | (l[1] << 16), l[2] | (l[3] << 16),
                  l[4] | (l[5] << 16), l[6] | (l[7] << 16));
}

__global__ __attribute__((amdgpu_waves_per_eu(2, 2))) __launch_bounds__(256)
void fused_ac(
    const float* __restrict__ x,   const float* __restrict__ actv,
    const float* __restrict__ cW1, const float* __restrict__ cb1, const float* __restrict__ cg1,
    const float* __restrict__ cW2, const float* __restrict__ cb2,
    const float* __restrict__ cW3, const float* __restrict__ cb3,
    const float* __restrict__ aW1, const float* __restrict__ ab1,
    const float* __restrict__ aW2, const float* __restrict__ ab2,
    const float* __restrict__ amW, const float* __restrict__ amb,
    const float* __restrict__ nW1, const float* __restrict__ nb1, const float* __restrict__ ng1,
    const float* __restrict__ nW2, const float* __restrict__ nb2, const float* __restrict__ ng2,
    const float* __restrict__ nfW, const float* __restrict__ nfb,
    float* __restrict__ out)
{
  extern __shared__ float sm[];
  const int tid  = (int)threadIdx.x;
  const int tc   = tid & 15;     // col group (16)
  const int tr   = tid >> 4;     // row group (16)
  const int lane = tid & 63;
  const int wv   = tid >> 6;
  const long rowbase = (long)blockIdx.x << 6;

  // ---- stage small params / compute amW row norms ----
  if (tid < 64) {
    sm[SBX + 0*64 + tid] = cb1[tid];
    sm[SBX + 1*64 + tid] = cg1[tid];
    sm[SBX + 2*64 + tid] = ab1[tid];
    sm[SBX + 3*64 + tid] = nb1[tid];
    sm[SBX + 4*64 + tid] = ng1[tid];
    sm[SBX + 5*64 + tid] = cb2[tid];
    sm[SBX + 6*64 + tid] = ab2[tid];
    sm[SBX + 7*64 + tid] = nb2[tid];
    sm[SBX + 8*64 + tid] = ng2[tid];
    sm[SBX + 9*64 + tid] = nfb[tid];
    sm[SCW3 + tid] = cW3[tid];
  } else if (tid < 81) {
    sm[SAMB + (tid - 64)] = amb[tid - 64];
  } else if (tid == 81) {
    sm[SCB3] = cb3[0];
  } else if (tid >= 128 && tid < 145) {
    const int a = tid - 128;
    float s = 0.0f;
    for (int h = 0; h < 64; ++h) { const float w = amW[a*64 + h]; s = fmaf(w, w, s); }
    sm[SRN + a] = 1.0f / (sqrtf(s) + 1e-8f);
  }

  // =================== P1: trunk GEMM on MFMA (split-bf16) ===================
  // Y[64][192] = X[64][384pad] @ WT[384][192];  wave wv owns cols 48*wv..+47
  f32x4 acc[4][3];
  #pragma unroll
  for (int mt = 0; mt < 4; ++mt)
    #pragma unroll
    for (int n = 0; n < 3; ++n)
      acc[mt][n] = (f32x4){0.f, 0.f, 0.f, 0.f};

  for (int ch = 0; ch < 6; ++ch) {       // K chunks of 64 (8 k8-groups)
    __syncthreads();                     // staging overwrite vs prev mfma reads
    // ---- stage x: 512 (row,k8) groups, 2 per thread, frag order + XOR swz ----
    #pragma unroll
    for (int pi = 0; pi < 2; ++pi) {
      const int p = 2*tid + pi;
      const int row = p >> 3, k8l = p & 7;
      const int k8 = ch*8 + k8l;
      float v[8];
      if (k8 < 47) {
        const float* xp = &x[(rowbase + row)*OBSD + k8*8];
        F4 u0, u1; u0.v = *(const float4*)xp; u1.v = *(const float4*)(xp + 4);
        #pragma unroll
        for (int j = 0; j < 4; ++j) { v[j] = u0.a[j]; v[4 + j] = u1.a[j]; }
      } else {
        #pragma unroll
        for (int j = 0; j < 8; ++j) v[j] = 0.f;
      }
      uint4 ph, pl; split8(v, ph, pl);
      const int s  = k8l >> 2;
      const int lw = ((k8l & 3) << 4) | (row & 15);
      const int boff = ((((row >> 4)*2 + s)*64 + lw) << 4) ^ ((k8l & 7) << 4);
      *(uint4*)((char*)&sm[XH] + boff) = ph;
      *(uint4*)((char*)&sm[XL] + boff) = pl;
    }
    // ---- stage W: 1536 (col,k8) groups, 6 per thread ----
    #pragma unroll
    for (int i = 0; i < 6; ++i) {
      const int p = tid + (i << 8);
      const int col = p >> 3, k8l = p & 7;
      const int k8 = ch*8 + k8l;
      const float* wsrc = (col < 64) ? cW1 : ((col < 128) ? aW1 : nW1);
      float v[8];
      if (k8 < 47) {
        const float* wp = &wsrc[(col & 63)*OBSD + k8*8];
        F4 u0, u1; u0.v = *(const float4*)wp; u1.v = *(const float4*)(wp + 4);
        #pragma unroll
        for (int j = 0; j < 4; ++j) { v[j] = u0.a[j]; v[4 + j] = u1.a[j]; }
      } else {
        #pragma unroll
        for (int j = 0; j < 8; ++j) v[j] = 0.f;
      }
      uint4 ph, pl; split8(v, ph, pl);
      const int s  = k8l >> 2;
      const int lw = ((k8l & 3) << 4) | (col & 15);
      const int boff = ((((col >> 4)*2 + s)*64 + lw) << 4) ^ ((k8l & 7) << 4);
      *(uint4*)((char*)&sm[WHS] + boff) = ph;
      *(uint4*)((char*)&sm[WLS] + boff) = pl;
    }
    __syncthreads();
    // ---- MFMA: 2 k-steps x 12 tiles x 3 split-products ----
    #pragma unroll
    for (int s = 0; s < 2; ++s) {
      const int xorv = ((s << 2) | (lane >> 4)) << 4;
      bf16x8 ah[4], al[4];
      #pragma unroll
      for (int mt = 0; mt < 4; ++mt) {
        const int boff = (((mt*2 + s)*64 + lane) << 4) ^ xorv;
        ah[mt] = *(const bf16x8*)((const char*)&sm[XH] + boff);
        al[mt] = *(const bf16x8*)((const char*)&sm[XL] + boff);
      }
      bf16x8 bh[3], bl[3];
      #pragma unroll
      for (int n = 0; n < 3; ++n) {
        const int nt = 3*wv + n;
        const int boff = (((nt*2 + s)*64 + lane) << 4) ^ xorv;
        bh[n] = *(const bf16x8*)((const char*)&sm[WHS] + boff);
        bl[n] = *(const bf16x8*)((const char*)&sm[WLS] + boff);
      }
      #pragma unroll
      for (int mt = 0; mt < 4; ++mt)
        #pragma unroll
        for (int n = 0; n < 3; ++n) {
          acc[mt][n] = __builtin_amdgcn_mfma_f32_16x16x32_bf16(ah[mt], bh[n], acc[mt][n], 0, 0, 0);
          acc[mt][n] = __builtin_amdgcn_mfma_f32_16x16x32_bf16(ah[mt], bl[n], acc[mt][n], 0, 0, 0);
          acc[mt][n] = __builtin_amdgcn_mfma_f32_16x16x32_bf16(al[mt], bh[n], acc[mt][n], 0, 0, 0);
        }
    }
  }
  __syncthreads();
  // D-frags -> ATT transposed tiles [t][h][row] (aliases staging, now dead)
  #pragma unroll
  for (int mt = 0; mt < 4; ++mt)
    #pragma unroll
    for (int n = 0; n < 3; ++n) {
      const int col = (3*wv + n)*16 + (lane & 15);
      const int t = col >> 6, h = col & 63;
      const int row0 = mt*16 + ((lane >> 4) << 2);
      float4 d;
      d.x = acc[mt][n][0]; d.y = acc[mt][n][1];
      d.z = acc[mt][n][2]; d.w = acc[mt][n][3];
      *(float4*)&sm[ATT + t*4352 + h*68 + row0] = d;
    }
  __syncthreads();

  // =================== E1: silu (+rms) in place ===================
  #pragma unroll 1
  for (int rb = 0; rb < 4; ++rb) {
    const int r0 = wv*16 + rb*4;
    { // critic: rmsnorm(silu(.+cb1), cg1)
      F4 y; y.v = *(const float4*)&sm[ATT + 0*4352 + lane*68 + r0];
      const float b = sm[SBX + 0*64 + lane], g = sm[SBX + 1*64 + lane];
      float vv[4], ss[4];
      #pragma unroll
      for (int rr = 0; rr < 4; ++rr) { const float s = silu_f(y.a[rr] + b); vv[rr] = s; ss[rr] = s*s; }
      #pragma unroll
      for (int m = 1; m < 64; m <<= 1)
        #pragma unroll
        for (int rr = 0; rr < 4; ++rr) ss[rr] += __shfl_xor(ss[rr], m, 64);
      F4 o;
      #pragma unroll
      for (int rr = 0; rr < 4; ++rr) o.a[rr] = vv[rr] * rsqrtf(ss[rr]*(1.0f/64.0f) + EPS_RMS) * g;
      *(float4*)&sm[ATT + 0*4352 + lane*68 + r0] = o.v;
    }
    { // actor: silu only
      F4 y; y.v = *(const float4*)&sm[ATT + 1*4352 + lane*68 + r0];
      const float b = sm[SBX + 2*64 + lane];
      F4 o;
      #pragma unroll
      for (int rr = 0; rr < 4; ++rr) o.a[rr] = silu_f(y.a[rr] + b);
      *(float4*)&sm[ATT + 1*4352 + lane*68 + r0] = o.v;
    }
    { // noise: rmsnorm(silu(.+nb1), ng1)
      F4 y; y.v = *(const float4*)&sm[ATT + 2*4352 + lane*68 + r0];
      const float b = sm[SBX + 3*64 + lane], g = sm[SBX + 4*64 + lane];
      float vv[4], ss[4];
      #pragma unroll
      for (int rr = 0; rr < 4; ++rr) { const float s = silu_f(y.a[rr] + b); vv[rr] = s; ss[rr] = s*s; }
      #pragma unroll
      for (int m = 1; m < 64; m <<= 1)
        #pragma unroll
        for (int rr = 0; rr < 4; ++rr) ss[rr] += __shfl_xor(ss[rr], m, 64);
      F4 o;
      #pragma unroll
      for (int rr = 0; rr < 4; ++rr) o.a[rr] = vv[rr] * rsqrtf(ss[rr]*(1.0f/64.0f) + EPS_RMS) * g;
      *(float4*)&sm[ATT + 2*4352 + lane*68 + r0] = o.v;
    }
  }
  __syncthreads();

  // =================== P2: three 64x64 GEMMs (VALU) ===================
  float acc2_0[4][4], acc2_1[4][4], acc2_2[4][4];
  #pragma unroll
  for (int cc = 0; cc < 4; ++cc)
    #pragma unroll
    for (int rr = 0; rr < 4; ++rr) { acc2_0[cc][rr] = 0.f; acc2_1[cc][rr] = 0.f; acc2_2[cc][rr] = 0.f; }

#define GEMM2_STEP(T, WP, ACC) do {                                              \
    for (int i = tid; i < 4096; i += 256) {                                      \
      const int j = i >> 6, h = i & 63;                                          \
      sm[WSTO + h*68 + (j ^ ((h & 7) << 2))] = (WP)[i];                          \
    }                                                                            \
    __syncthreads();                                                             \
    for (int h = 0; h < 64; ++h) {                                               \
      F4 a4; a4.v = *(const float4*)&sm[ATT + (T)*4352 + h*68 + 4*tr];           \
      F4 w4; w4.v = *(const float4*)&sm[WSTO + h*68 + ((4*tc) ^ ((h & 7) << 2))];\
      _Pragma("unroll")                                                          \
      for (int cc = 0; cc < 4; ++cc)                                             \
        _Pragma("unroll")                                                        \
        for (int rr = 0; rr < 4; ++rr)                                           \
          ACC[cc][rr] = fmaf(w4.a[cc], a4.a[rr], ACC[cc][rr]);                   \
    }                                                                            \
    __syncthreads();                                                             \
  } while (0)

  GEMM2_STEP(0, cW2, acc2_0);
  GEMM2_STEP(1, aW2, acc2_1);
  GEMM2_STEP(2, nW2, acc2_2);

#define ST_A2T(T, ACC) do {                                                      \
    _Pragma("unroll")                                                            \
    for (int cc = 0; cc < 4; ++cc) {                                             \
      const int j = 4*tc + cc;                                                   \
      F4 v;                                                                      \
      _Pragma("unroll")                                                          \
      for (int rr = 0; rr < 4; ++rr) v.a[rr] = ACC[cc][rr];                      \
      *(float4*)&sm[ATT + (T)*4352 + j*68 + 4*tr] = v.v;                         \
    }                                                                            \
  } while (0)
  ST_A2T(0, acc2_0);
  ST_A2T(1, acc2_1);
  ST_A2T(2, acc2_2);
  __syncthreads();

  // =================== E2: activations + value output ===================
  #pragma unroll 1
  for (int rb = 0; rb < 4; ++rb) {
    const int r0 = wv*16 + rb*4;
    { // critic: value = sum(silu(.+cb2) * cW3) + cb3
      F4 y; y.v = *(const float4*)&sm[ATT + 0*4352 + lane*68 + r0];
      const float b = sm[SBX + 5*64 + lane], w3 = sm[SCW3 + lane];
      float pv[4];
      #pragma unroll
      for (int rr = 0; rr < 4; ++rr) pv[rr] = silu_f(y.a[rr] + b) * w3;
      #pragma unroll
      for (int m = 1; m < 64; m <<= 1)
        #pragma unroll
        for (int rr = 0; rr < 4; ++rr) pv[rr] += __shfl_xor(pv[rr], m, 64);
      if (lane == 0) {
        const float c3 = sm[SCB3];
        #pragma unroll
        for (int rr = 0; rr < 4; ++rr)
          out[(size_t)BB*19 + (size_t)(rowbase + r0 + rr)] = pv[rr] + c3;
      }
    }
    { // actor: l2 = silu(.+ab2)
      F4 y; y.v = *(const float4*)&sm[ATT + 1*4352 + lane*68 + r0];
      const float b = sm[SBX + 6*64 + lane];
      F4 o;
      #pragma unroll
      for (int rr = 0; rr < 4; ++rr) o.a[rr] = silu_f(y.a[rr] + b);
      *(float4*)&sm[ATT + 1*4352 + lane*68 + r0] = o.v;
    }
    { // noise: n2 = rmsnorm(silu(.+nb2), ng2)
      F4 y; y.v = *(const float4*)&sm[ATT + 2*4352 + lane*68 + r0];
      const float b = sm[SBX + 7*64 + lane], g = sm[SBX + 8*64 + lane];
      float vv[4], ss[4];
      #pragma unroll
      for (int rr = 0; rr < 4; ++rr) { const float s = silu_f(y.a[rr] + b); vv[rr] = s; ss[rr] = s*s; }
      #pragma unroll
      for (int m = 1; m < 64; m <<= 1)
        #pragma unroll
        for (int rr = 0; rr < 4; ++rr) ss[rr] += __shfl_xor(ss[rr], m, 64);
      F4 o;
      #pragma unroll
      for (int rr = 0; rr < 4; ++rr) o.a[rr] = vv[rr] * rsqrtf(ss[rr]*(1.0f/64.0f) + EPS_RMS) * g;
      *(float4*)&sm[ATT + 2*4352 + lane*68 + r0] = o.v;
    }
  }
  __syncthreads();

  // =================== P3: nfW GEMM + heads ===================
  for (int i = tid; i < 4096; i += 256) {
    const int j = i >> 6, h = i & 63;
    sm[WSTO + h*68 + (j ^ ((h & 7) << 2))] = nfW[i];
  }
  for (int i = tid; i < 1088; i += 256) {
    const int a = i >> 6, h = i & 63;
    sm[WHDO + h*20 + a] = amW[i];
  }
  __syncthreads();

  float acc3n[4][4];
  #pragma unroll
  for (int cc = 0; cc < 4; ++cc)
    #pragma unroll
    for (int rr = 0; rr < 4; ++rr) acc3n[cc][rr] = 0.f;
  for (int h = 0; h < 64; ++h) {
    F4 a4; a4.v = *(const float4*)&sm[ATT + 2*4352 + h*68 + 4*tr];
    F4 w4; w4.v = *(const float4*)&sm[WSTO + h*68 + ((4*tc) ^ ((h & 7) << 2))];
    #pragma unroll
    for (int cc = 0; cc < 4; ++cc)
      #pragma unroll
      for (int rr = 0; rr < 4; ++rr) acc3n[cc][rr] = fmaf(w4.a[cc], a4.a[rr], acc3n[cc][rr]);
  }
  float acc3h[4][4];
  #pragma unroll
  for (int cc = 0; cc < 4; ++cc)
    #pragma unroll
    for (int rr = 0; rr < 4; ++rr) acc3h[cc][rr] = 0.f;
  if (tc < 5) {
    for (int h = 0; h < 64; ++h) {
      F4 a4; a4.v = *(const float4*)&sm[ATT + 1*4352 + h*68 + 4*tr];
      F4 w4; w4.v = *(const float4*)&sm[WHDO + h*20 + 4*tc];
      #pragma unroll
      for (int cc = 0; cc < 4; ++cc)
        #pragma unroll
        for (int rr = 0; rr < 4; ++rr) acc3h[cc][rr] = fmaf(w4.a[cc], a4.a[rr], acc3h[cc][rr]);
    }
  }
  __syncthreads();

  // sigma^2 tile into WSTO (nfW staging dead)
  #pragma unroll
  for (int cc = 0; cc < 4; ++cc) {
    const int j = 4*tc + cc;
    const float nb = sm[SBX + 9*64 + j];
    F4 v;
    #pragma unroll
    for (int rr = 0; rr < 4; ++rr)
      v.a[rr] = expf(2.0f * fminf(acc3n[cc][rr] + nb, 5.0f));
    *(float4*)&sm[WSTO + j*68 + 4*tr] = v.v;
  }
  // heads epilogue: action copy + diff into WHDO (amW^T staging dead)
  if (tc < 5) {
    #pragma unroll
    for (int cc = 0; cc < 4; ++cc) {
      const int c = 4*tc + cc;
      if (c < 17) {
        const float mb = sm[SAMB + c];
        #pragma unroll
        for (int rr = 0; rr < 4; ++rr) {
          const int lr = 4*tr + rr;
          const size_t grow = (size_t)(rowbase + lr);
          const float mean = acc3h[cc][rr] + mb;
          const float av = actv[grow*17 + c];
          out[grow*17 + c] = av;
          sm[WHDO + lr*20 + c] = av - mean;
        }
      }
    }
  }
  // pair-product table PT[h][p] into ATT region (A2T dead)
  for (int i = tid; i < 9792; i += 256) {
    const int h = i / 153;
    const int p = i - h*153;
    int a = (int)((sqrtf(8.0f*(float)p + 1.0f) - 1.0f) * 0.5f);
    if ((a + 1)*(a + 2)/2 <= p) ++a;
    if (a*(a + 1)/2 > p) --a;
    const int c = p - a*(a + 1)/2;
    sm[PTB + h*192 + p] = amW[a*64 + h] * amW[c*64 + h] * sm[SRN + a] * sm[SRN + c];
  }
  __syncthreads();

  // =================== P4: gram GEMM [64,64]@[64,153] (VALU) ===================
  float acc4[12][4];
  #pragma unroll
  for (int cc = 0; cc < 12; ++cc)
    #pragma unroll
    for (int rr = 0; rr < 4; ++rr) acc4[cc][rr] = 0.f;
  for (int h = 0; h < 64; ++h) {
    F4 s4; s4.v = *(const float4*)&sm[WSTO + h*68 + 4*tr];
    const float* pp = &sm[PTB + h*192 + 12*tc];
    F4 p0, p1, p2;
    p0.v = *(const float4*)(pp + 0);
    p1.v = *(const float4*)(pp + 4);
    p2.v = *(const float4*)(pp + 8);
    #pragma unroll
    for (int cc = 0; cc < 4; ++cc)
      #pragma unroll
      for (int rr = 0; rr < 4; ++rr) {
        acc4[cc + 0][rr] = fmaf(p0.a[cc], s4.a[rr], acc4[cc + 0][rr]);
        acc4[cc + 4][rr] = fmaf(p1.a[cc], s4.a[rr], acc4[cc + 4][rr]);
        acc4[cc + 8][rr] = fmaf(p2.a[cc], s4.a[rr], acc4[cc + 8][rr]);
      }
  }
  __syncthreads();
  #pragma unroll
  for (int cc = 0; cc < 12; ++cc) {
    const int p = 12*tc + cc;
    if (p < 153) {
      #pragma unroll
      for (int rr = 0; rr < 4; ++rr)
        sm[GBB + (4*tr + rr)*154 + p] = acc4[cc][rr];
    }
  }
  __syncthreads();

  // =================== P5: Cholesky + solve, 17-lane groups ===================
  {
    const int g  = lane / 17;        // 0..3 (g==3 idle)
    const int j  = lane - g*17;      // 0..16
    const int gb = g*17;
    const int jb = j*(j + 1)/2;
    #pragma unroll 1
    for (int t6 = 0; t6 < 6; ++t6) {
      const int rl = 3*t6 + g;
      const bool valid = (g < 3) && (rl < 16);
      const int rloc = wv*16 + (valid ? rl : 0);
      float L[17];
      #pragma unroll
      for (int i = 0; i <= 16; ++i) {
        const float vv = (j >= i) ? sm[GBB + rloc*154 + jb + i] : 0.0f;
        L[i] = vv + ((i == j) ? 1e-4f : 0.0f);
      }
      float d = sm[WHDO + rloc*20 + j];
      float mylog = 0.0f, myinv = 0.0f, yown = 0.0f;
      #pragma unroll
      for (int k = 0; k <= 16; ++k) {
        const float akk = __shfl(L[k], gb + k, 64);
        const float rsq = rsqrtf(akk);
        if (j == k) { L[k] = akk * rsq; mylog = 0.5f * logf(akk); myinv = rsq; }
        if (j > k)  { L[k] *= rsq; }
        #pragma unroll
        for (int i = k + 1; i <= 16; ++i) {
          const float lik = __shfl(L[k], gb + i, 64);
          if (j >= i) L[i] = fmaf(-L[k], lik, L[i]);
        }
      }
      #pragma unroll
      for (int i = 0; i <= 16; ++i) {
        const float yi = __shfl(d * myinv, gb + i, 64);
        if (j == i) yown = yi;
        if (j > i)  d = fmaf(-L[i], yi, d);
      }
      const float y2 = yown * yown;
      float ms = 0.0f, ls = 0.0f;
      #pragma unroll
      for (int jj = 0; jj <= 16; ++jj) {
        ms += __shfl(y2,    gb + jj, 64);
        ls += __shfl(mylog, gb + jj, 64);
      }
      if (valid && j == 0) {
        const size_t grow = (size_t)(rowbase + rloc);
        out[(size_t)BB*17 + grow] = -0.5f * (17.0f*LOG2PI_F + 2.0f*ls + ms);
        out[(size_t)BB*18 + grow] =  0.5f * (17.0f*(1.0f + LOG2PI_F) + 2.0f*ls);
      }
    }
  }
}

extern "C" void kernel_launch(void* const* d_in, const int* in_sizes, int n_in,
                              void* d_out, int out_size, void* d_ws, size_t ws_size,
                              hipStream_t stream) {
  (void)in_sizes; (void)n_in; (void)d_ws; (void)ws_size; (void)out_size;
  const float* x   = (const float*)d_in[0];
  const float* acv = (const float*)d_in[1];
  const float* cW1 = (const float*)d_in[2];
  const float* cb1 = (const float*)d_in[3];
  const float* cg1 = (const float*)d_in[4];
  const float* cW2 = (const float*)d_in[5];
  const float* cb2 = (const float*)d_in[6];
  const float* cW3 = (const float*)d_in[7];
  const float* cb3 = (const float*)d_in[8];
  const float* aW1 = (const float*)d_in[9];
  const float* ab1 = (const float*)d_in[10];
  const float* aW2 = (const float*)d_in[11];
  const float* ab2 = (const float*)d_in[12];
  const float* amW = (const float*)d_in[13];
  const float* amb = (const float*)d_in[14];
  const float* nW1 = (const float*)d_in[15];
  const float* nb1 = (const float*)d_in[16];
  const float* ng1 = (const float*)d_in[17];
  const float* nW2 = (const float*)d_in[18];
  const float* nb2 = (const float*)d_in[19];
  const float* ng2 = (const float*)d_in[20];
  const float* nfW = (const float*)d_in[21];
  const float* nfb = (const float*)d_in[22];
  float* out = (float*)d_out;

  const int smem_bytes = SMEMF * 4;
  hipFuncSetAttribute((const void*)fused_ac,
                      hipFuncAttributeMaxDynamicSharedMemorySize, smem_bytes);
  fused_ac<<<dim3(BB/64), dim3(256), smem_bytes, stream>>>(
      x, acv, cW1, cb1, cg1, cW2, cb2, cW3, cb3,
      aW1, ab1, aW2, ab2, amW, amb,
      nW1, nb1, ng1, nW2, nb2, ng2, nfW, nfb, out);
}